// Round 2
// baseline (152.394 us; speedup 1.0000x reference)
//
#include <hip/hip_runtime.h>
#include <math.h>

// NaiveDFTQNN: 25-wire state vector, DIM = 2^25.
// out = (cos(theta0/2)/||f||) * (tensor product of 12 Givens rotations) * f
// Pair j (j=0..11) acts on little-endian element bits (2j+1, 2j), angle theta[11-j]/2:
//   v=01: n01 = c*a01 - s*a10 ; v=10: n10 = s*a01 + c*a10 ; v=00,11 untouched.
// Bit 24 (wire 0) is a spectator (RX folds into the scalar).
//
// Pass 1 (qnn_high): tile = 1024 combos of bits 14..23 x 16-float payload (bits 0..3).
//   Handles pairs j=7..11 (bits 14..23) AND j=0,1 (payload) + sum-of-squares partials.
// Pass 2 (qnn_low): contiguous 16384-float tile (bits 0..13). Handles j=2..6 + scale.
//
// Occupancy design: 1024 thr/block, 4 float4/thread, 64KB LDS -> 2 blocks/CU = 32
// waves/CU if VGPR<=64. 3 of the in-tile pairs per kernel are done with lane
// shuffles / register pairs; only 2 LDS round-trips (2 barriers). Every LDS access
// keeps slot == lane (mod 64) -> conflict-free linear layout, no swizzle.

static __device__ __forceinline__ void rot4(float4& a, float4& b, float c, float s) {
    float4 na, nb;
    na.x = c*a.x - s*b.x;  nb.x = s*a.x + c*b.x;
    na.y = c*a.y - s*b.y;  nb.y = s*a.y + c*b.y;
    na.z = c*a.z - s*b.z;  nb.z = s*a.z + c*b.z;
    na.w = c*a.w - s*b.w;  nb.w = s*a.w + c*b.w;
    a = na; b = nb;
}

static __device__ __forceinline__ float4 shflx4(float4 v, int m) {
    float4 r;
    r.x = __shfl_xor(v.x, m, 64);
    r.y = __shfl_xor(v.y, m, 64);
    r.z = __shfl_xor(v.z, m, 64);
    r.w = __shfl_xor(v.w, m, 64);
    return r;
}

// Givens pair on lane bits (sh+1, sh): pv = (lane>>sh)&3; lanes 01/10 exchange with
// partner lane^(3<<sh). Branchless: n = cl*own + sl*partner with per-lane (cl,sl).
static __device__ __forceinline__ void rotshfl(float4* f, int sh, float c, float s, int lane) {
    const int pv = (lane >> sh) & 3;
    const bool act = (pv == 1) || (pv == 2);
    const float cl = act ? c : 1.0f;
    const float sl = act ? ((pv == 1) ? -s : s) : 0.0f;
    const int m = 3 << sh;
#pragma unroll
    for (int k = 0; k < 4; ++k) {
        float4 p = shflx4(f[k], m);
        float4 n;
        n.x = fmaf(sl, p.x, cl * f[k].x);
        n.y = fmaf(sl, p.y, cl * f[k].y);
        n.z = fmaf(sl, p.z, cl * f[k].z);
        n.w = fmaf(sl, p.w, cl * f[k].w);
        f[k] = n;
    }
}

// ---------------- Pass 1: bits 14..23 pairs + j=0,1 + norm partials ----------------
__global__ __launch_bounds__(1024, 8) void qnn_high(const float* __restrict__ in,
                                                    const float* __restrict__ theta,
                                                    float* __restrict__ out,
                                                    double* __restrict__ partials) {
    __shared__ __align__(16) float4 lds[4096];   // 64 KB
    __shared__ double red[16];
    const int t = threadIdx.x, lane = t & 63;
    const int blk = blockIdx.x;
    // XCD-chunked swizzle (2048 % 8 == 0 -> bijective): consecutive logical ids
    // (adjacent chunks, sharing 128B lines in the 64B-granule gather) on one XCD.
    const int logical = (blk & 7) * 256 + (blk >> 3);
    const int chunk = logical & 1023;           // element bits 4..13
    const int b24 = logical >> 10;              // spectator bit 24
    const long fb = ((long)b24 << 22) | ((long)chunk << 2);  // float4-index base

    // angles: idx 0..4 = high pairs jj (element bits 14+2jj+1,14+2jj) -> theta[4-jj];
    //         idx 5 = j0 -> theta[11]; idx 6 = j1 -> theta[10]
    float cA[7], sA[7];
    {
        float th;
        th = 0.5f*theta[4];  cA[0]=cosf(th); sA[0]=sinf(th);
        th = 0.5f*theta[3];  cA[1]=cosf(th); sA[1]=sinf(th);
        th = 0.5f*theta[2];  cA[2]=cosf(th); sA[2]=sinf(th);
        th = 0.5f*theta[1];  cA[3]=cosf(th); sA[3]=sinf(th);
        th = 0.5f*theta[0];  cA[4]=cosf(th); sA[4]=sinf(th);
        th = 0.5f*theta[11]; cA[5]=cosf(th); sA[5]=sinf(th);
        th = 0.5f*theta[10]; cA[6]=cosf(th); sA[6]=sinf(th);
    }

    // slot w = k*1024 + t, w = (h<<2)|p: h = bits 14..23 combo, p = payload quad.
    // lane bits: p = lane bits 0,1; h bits 0..3 = lane bits 2..5. k = h bits 9,8.
    float4 f[4];
    double acc = 0.0;
#pragma unroll
    for (int k = 0; k < 4; ++k) {
        const int w = k * 1024 + t;
        const int h = w >> 2, p = w & 3;
        f[k] = *(const float4*)(in + ((fb + ((long)h << 12) + p) << 2));
        acc += (double)f[k].x*f[k].x + (double)f[k].y*f[k].y
             + (double)f[k].z*f[k].z + (double)f[k].w*f[k].w;
    }
    // j=0: element bits (1,0) = float4 components 1,2
#pragma unroll
    for (int k = 0; k < 4; ++k) {
        float ny = cA[5]*f[k].y - sA[5]*f[k].z;
        float nz = sA[5]*f[k].y + cA[5]*f[k].z;
        f[k].y = ny; f[k].z = nz;
    }
    rotshfl(f, 0, cA[6], sA[6], lane);   // j=1  (p = lane bits 1,0)
    rotshfl(f, 2, cA[0], sA[0], lane);   // jj=0 (h bits 1,0 = lane bits 3,2)
    rotshfl(f, 4, cA[1], sA[1], lane);   // jj=1 (h bits 3,2 = lane bits 5,4)
    rot4(f[1], f[2], cA[4], sA[4]);      // jj=4 (h bits 9,8 = k)

#pragma unroll
    for (int k = 0; k < 4; ++k) lds[k * 1024 + t] = f[k];
    __syncthreads();
    {   // jj=2: slot bits 7,6 (h bits 5,4)
        const int sb = ((t >> 6) << 8) | (t & 63);
#pragma unroll
        for (int b = 0; b < 4; ++b) f[b] = lds[sb | (b << 6)];
        rot4(f[1], f[2], cA[2], sA[2]);
#pragma unroll
        for (int b = 0; b < 4; ++b) lds[sb | (b << 6)] = f[b];
    }
    __syncthreads();
    {   // jj=3: slot bits 9,8 (h bits 7,6) + global store
        const int sb = ((t >> 8) << 10) | (t & 255);
#pragma unroll
        for (int b = 0; b < 4; ++b) f[b] = lds[sb | (b << 8)];
        rot4(f[1], f[2], cA[3], sA[3]);
#pragma unroll
        for (int b = 0; b < 4; ++b) {
            const int w = sb | (b << 8);
            const int h = w >> 2, p = w & 3;
            *(float4*)(out + ((fb + ((long)h << 12) + p) << 2)) = f[b];
        }
    }
    // deterministic sum-of-squares partial
#pragma unroll
    for (int off = 32; off > 0; off >>= 1) acc += __shfl_down(acc, off, 64);
    if (lane == 0) red[t >> 6] = acc;
    __syncthreads();
    if (t == 0) {
        double s = 0.0;
#pragma unroll
        for (int i = 0; i < 16; ++i) s += red[i];
        partials[blk] = s;
    }
}

// ---------------- Norm: 2048 partials -> scale = cos(theta0/2)/sqrt(sum) ----------
__global__ void qnn_norm(const double* __restrict__ partials,
                         const float* __restrict__ theta,
                         double* __restrict__ scale) {
    __shared__ double w[4];
    const int t = threadIdx.x;
    double acc = 0.0;
    for (int i = t; i < 2048; i += 256) acc += partials[i];
#pragma unroll
    for (int off = 32; off > 0; off >>= 1) acc += __shfl_down(acc, off, 64);
    if ((t & 63) == 0) w[t >> 6] = acc;
    __syncthreads();
    if (t == 0) {
        double tot = w[0] + w[1] + w[2] + w[3];
        *scale = (double)cosf(0.5f * theta[0]) / sqrt(tot);
    }
}

// ---------------- Pass 2: pairs j=2..6 (bits 4..13) + scale, in place -------------
__global__ __launch_bounds__(1024, 8) void qnn_low(float* __restrict__ buf,
                                                   const float* __restrict__ theta,
                                                   const double* __restrict__ scale) {
    __shared__ __align__(16) float4 lds[4096];   // 64 KB
    const int t = threadIdx.x, lane = t & 63;
    const long gfb = (long)blockIdx.x << 12;     // float4-index base (contiguous tile)

    // i = 0..4 <-> pair j=i+2 (element bits 2j+1,2j) <-> theta[9-i]
    float cB[5], sB[5];
    {
        float th;
        th = 0.5f*theta[9]; cB[0]=cosf(th); sB[0]=sinf(th);
        th = 0.5f*theta[8]; cB[1]=cosf(th); sB[1]=sinf(th);
        th = 0.5f*theta[7]; cB[2]=cosf(th); sB[2]=sinf(th);
        th = 0.5f*theta[6]; cB[3]=cosf(th); sB[3]=sinf(th);
        th = 0.5f*theta[5]; cB[4]=cosf(th); sB[4]=sinf(th);
    }
    const float sc = (float)(*scale);

    // slot w = k*1024 + t = element bits 2..13. lane = slot bits 0..5, k = bits 11,10.
    float4 f[4];
#pragma unroll
    for (int k = 0; k < 4; ++k)
        f[k] = *(const float4*)(buf + ((gfb + k * 1024 + t) << 2));

    rotshfl(f, 2, cB[0], sB[0], lane);   // j=2 (slot bits 3,2 = lane bits 3,2)
    rotshfl(f, 4, cB[1], sB[1], lane);   // j=3 (slot bits 5,4 = lane bits 5,4)
    rot4(f[1], f[2], cB[4], sB[4]);      // j=6 (slot bits 11,10 = k)

#pragma unroll
    for (int k = 0; k < 4; ++k) lds[k * 1024 + t] = f[k];
    __syncthreads();
    {   // j=4: slot bits 7,6
        const int sb = ((t >> 6) << 8) | (t & 63);
#pragma unroll
        for (int b = 0; b < 4; ++b) f[b] = lds[sb | (b << 6)];
        rot4(f[1], f[2], cB[2], sB[2]);
#pragma unroll
        for (int b = 0; b < 4; ++b) lds[sb | (b << 6)] = f[b];
    }
    __syncthreads();
    {   // j=5: slot bits 9,8 + scale + store
        const int sb = ((t >> 8) << 10) | (t & 255);
#pragma unroll
        for (int b = 0; b < 4; ++b) f[b] = lds[sb | (b << 8)];
        rot4(f[1], f[2], cB[3], sB[3]);
#pragma unroll
        for (int b = 0; b < 4; ++b) {
            float4 v = f[b];
            v.x *= sc; v.y *= sc; v.z *= sc; v.w *= sc;
            *(float4*)(buf + ((gfb + (sb | (b << 8))) << 2)) = v;
        }
    }
}

extern "C" void kernel_launch(void* const* d_in, const int* in_sizes, int n_in,
                              void* d_out, int out_size, void* d_ws, size_t ws_size,
                              hipStream_t stream) {
    const float* in = (const float*)d_in[0];      // feature, 2^25 f32
    const float* theta = (const float*)d_in[1];   // 13 f32
    float* out = (float*)d_out;                   // 2^25 f32
    double* part = (double*)d_ws;                 // 2048 partials + 1 scale
    double* scale = part + 2048;

    qnn_high<<<2048, 1024, 0, stream>>>(in, theta, out, part);
    qnn_norm<<<1, 256, 0, stream>>>(part, theta, scale);
    qnn_low<<<2048, 1024, 0, stream>>>(out, theta, scale);
}